// Round 7
// baseline (306.990 us; speedup 1.0000x reference)
//
#include <hip/hip_runtime.h>
#include <cmath>

// Conductance-based LIF scan: T=512 steps, N=65536 neurons.
// R6: producer/consumer wave specialization. The T-scan is inherently
// sequential (spike resets), so parallelism is capped at N=65536 threads
// of consumer work = 4 waves/CU. To raise memory-pipe utilization we add
// 4 producer waves per WG that stage the next DBLK=16-step input block
// (3 arrays x 16 rows x 1KB = 48KB) into double-buffered LDS while
// consumers compute the current block from LDS and issue NT stores.
// Sync: raw s_barrier per block; producers drain lgkmcnt before it;
// consumers never drain vmcnt (NT stores stay in flight).
//
// Consumer numerics identical to the R5 kernel that passed with
// absmax 0.00390625: FMA-contracted, rcp-div, __expf. gA==0 elided.

#define DBLK 16        // time-steps per LDS block
#define CONS 256       // consumer threads (= neurons per WG)

typedef float f32x4 __attribute__((ext_vector_type(4)));

__global__ __launch_bounds__(512, 1) void lif_scan(
    const float* __restrict__ g_exc,
    const float* __restrict__ g_inh,
    const float* __restrict__ noise,
    const float* __restrict__ v_th,
    const float* __restrict__ tau_ref,
    float* __restrict__ out_spk,   // d_out[0 .. T*N)
    float* __restrict__ out_mem,   // d_out[T*N .. 2*T*N)
    int N, int T,
    float cGE, float cGI, float cALPHA, float cSIGMA)
{
    __shared__ float smem[2][3][DBLK][CONS];   // 96 KiB

    const int tid = threadIdx.x;
    const int wg  = blockIdx.x;
    const bool consumer = tid < CONS;
    const int NB = T / DBLK;                   // 32 blocks

    // ---- producer staging: thread p copies 12 float4s of block b ----
    // flat float4 index fi = j*256 + p over the 48KB block image
    // [a][r][64 f4]; a = fi>>10, r = (fi>>6)&15, q = fi&63.
    auto stage = [&](int b, int buf) {
        const int p = tid - CONS;              // 0..255
        #pragma unroll
        for (int j = 0; j < 12; ++j) {
            const int fi = j * 256 + p;
            const int a  = fi >> 10;
            const int r  = (fi >> 6) & 15;
            const int q  = fi & 63;
            const float* g = (a == 0) ? g_exc : (a == 1) ? g_inh : noise;
            const f32x4 val = *reinterpret_cast<const f32x4*>(
                g + (size_t)(b * DBLK + r) * (size_t)N + (size_t)wg * CONS + q * 4);
            *reinterpret_cast<f32x4*>(&smem[buf][a][r][q * 4]) = val;
        }
    };

    // ---- consumer state ----
    float v = 0.f, gE = 0.f, gI = 0.f, ref = 0.f, ou = 0.f;
    float vth = 1.0f, trf = 5.0f;
    const int n = wg * CONS + tid;
    if (consumer) { vth = v_th[n]; trf = tau_ref[n]; }

    auto step = [&](float ge_in, float gi_in, float z, int tt) {
        gE = __builtin_fmaf(gE, cGE, ge_in);
        gI = __builtin_fmaf(gI, cGI, gi_in);

        const float gt  = 1.0f + gE + gI;
        const float num = __builtin_fmaf(gI, -0.5f, gE * 3.0f);
        const float vinf = num * __builtin_amdgcn_rcpf(gt);

        const float decay = __expf(-0.05f * gt);

        v = __builtin_fmaf(v - vinf, decay, vinf);

        ou = __builtin_fmaf(ou, cALPHA, cSIGMA * z);
        v = v + ou;

        const bool in_ref = (ref > 0.0f);
        const bool spike  = (v >= vth) && (!in_ref);
        v = (in_ref || spike) ? 0.0f : v;
        ref = spike ? trf : fmaxf(ref - 1.0f, 0.0f);

        const size_t off = (size_t)tt * (size_t)N + (size_t)n;
        __builtin_nontemporal_store(spike ? 1.0f : 0.0f, out_spk + off);
        __builtin_nontemporal_store(v, out_mem + off);
    };

    // ---- prologue: producers fill buf0 with block 0 ----
    if (!consumer) {
        stage(0, 0);
        asm volatile("s_waitcnt lgkmcnt(0)" ::: "memory");
    }
    __builtin_amdgcn_s_barrier();
    asm volatile("" ::: "memory");

    // ---- pipeline: one barrier per block ----
    for (int b = 0; b < NB; ++b) {
        const int cur = b & 1;
        if (!consumer) {
            if (b + 1 < NB) stage(b + 1, cur ^ 1);
            asm volatile("s_waitcnt lgkmcnt(0)" ::: "memory");
        } else {
            #pragma unroll
            for (int r = 0; r < DBLK; ++r)
                step(smem[cur][0][r][tid], smem[cur][1][r][tid],
                     smem[cur][2][r][tid], b * DBLK + r);
        }
        __builtin_amdgcn_s_barrier();
        asm volatile("" ::: "memory");
    }
}

extern "C" void kernel_launch(void* const* d_in, const int* in_sizes, int n_in,
                              void* d_out, int out_size, void* d_ws, size_t ws_size,
                              hipStream_t stream) {
    const float* g_exc   = (const float*)d_in[0];
    const float* g_inh   = (const float*)d_in[1];
    const float* noise   = (const float*)d_in[2];
    const float* v_th    = (const float*)d_in[3];
    const float* tau_ref = (const float*)d_in[4];

    const int N = in_sizes[3];            // 65536
    const int T = in_sizes[0] / N;        // 512

    float* out_spk = (float*)d_out;
    float* out_mem = (float*)d_out + (size_t)T * (size_t)N;

    // Constants computed in double exactly as the Python reference does.
    const double ge_decay = exp(-1.0 / 5.0);
    const double gi_decay = exp(-1.0 / 10.0);
    const double ou_alpha = exp(-1.0 / 5.0);
    const double ou_sigma = 0.02 * sqrt(1.0 - ou_alpha * ou_alpha);

    const int block = 512;                 // 4 consumer + 4 producer waves
    const int grid = N / CONS;             // 256 WGs -> 1 per CU
    lif_scan<<<grid, block, 0, stream>>>(
        g_exc, g_inh, noise, v_th, tau_ref, out_spk, out_mem,
        N, T,
        (float)ge_decay, (float)gi_decay, (float)ou_alpha, (float)ou_sigma);
}

// Round 8
// 122.929 us; speedup vs baseline: 2.4973x; 2.4973x over previous
//
#include <hip/hip_runtime.h>
#include <cmath>

// Conductance-based LIF scan: T=512 steps, N=65536 neurons.
// R7: async self-staging pipeline. Keep R5's winning shape (256 thr/block,
// 1 neuron/lane, 1024 waves = 4/CU) but stream inputs through LDS with
// __builtin_amdgcn_global_load_lds (async, no VGPR roundtrip) and counted
// s_waitcnt vmcnt(N) that NEVER drains. Each wave stages only its own
// 64-lane slice into its own LDS quarter -> zero barriers, waves fully
// decoupled. Ring of D=8 steps (smem[8][3][256] = 24KB), processed in
// 4-step groups:
//   vmcnt(12) -> 12x ds_read_b32 (offset-imm) -> lgkmcnt(0)
//   -> issue 12 async loads into freed slots -> compute 4 steps + 8 NT st.
// vmcnt(12) is robust even if stores retire out-of-order vs loads: loads
// retire in order among themselves, so <=12 outstanding ops implies the
// previous batch's 12 loads have landed (the 12 newer loads alone would
// otherwise exceed 12).
//
// Numerics identical to R5 (passed, absmax 0.00390625): FMA-contracted,
// rcp-div, __expf. gA == 0 (ADAPT_INC==0), elided.

__device__ __forceinline__ void gload_lds(const float* g, float* l) {
    __builtin_amdgcn_global_load_lds(
        (const __attribute__((address_space(1))) unsigned int*)(const void*)g,
        (__attribute__((address_space(3))) unsigned int*)(void*)l,
        4, 0, 0);
}

__global__ __launch_bounds__(256, 1) void lif_scan(
    const float* __restrict__ g_exc,
    const float* __restrict__ g_inh,
    const float* __restrict__ noise,
    const float* __restrict__ v_th,
    const float* __restrict__ tau_ref,
    float* __restrict__ out_spk,   // d_out[0 .. T*N)
    float* __restrict__ out_mem,   // d_out[T*N .. 2*T*N)
    int N, int T,
    float cGE, float cGI, float cALPHA, float cSIGMA)
{
    __shared__ float smem[8][3][256];   // [slot][array][lane] = 24 KiB

    const int tid = threadIdx.x;
    const int wq  = (tid >> 6) << 6;            // this wave's LDS quarter base
    const int n   = blockIdx.x * 256 + tid;

    const float vth = v_th[n];
    const float trf = tau_ref[n];

    float v = 0.f, gE = 0.f, gI = 0.f, ref = 0.f, ou = 0.f;

    // stage steps t0..t0+3 into ring slots sb..sb+3 (12 async loads)
    auto issueB = [&](int t0, int sb) {
        #pragma unroll
        for (int k = 0; k < 4; ++k) {
            const size_t row = (size_t)(t0 + k) * (size_t)N + (size_t)n;
            gload_lds(g_exc + row, &smem[sb + k][0][wq]);
            gload_lds(g_inh + row, &smem[sb + k][1][wq]);
            gload_lds(noise + row, &smem[sb + k][2][wq]);
        }
    };

    auto step = [&](float ge_in, float gi_in, float z, int tt) {
        gE = __builtin_fmaf(gE, cGE, ge_in);
        gI = __builtin_fmaf(gI, cGI, gi_in);

        const float gt  = 1.0f + gE + gI;
        const float num = __builtin_fmaf(gI, -0.5f, gE * 3.0f);
        const float vinf = num * __builtin_amdgcn_rcpf(gt);

        const float decay = __expf(-0.05f * gt);

        v = __builtin_fmaf(v - vinf, decay, vinf);

        ou = __builtin_fmaf(ou, cALPHA, cSIGMA * z);
        v = v + ou;

        const bool in_ref = (ref > 0.0f);
        const bool spike  = (v >= vth) && (!in_ref);
        v = (in_ref || spike) ? 0.0f : v;
        ref = spike ? trf : fmaxf(ref - 1.0f, 0.0f);

        const size_t off = (size_t)tt * (size_t)N + (size_t)n;
        __builtin_nontemporal_store(spike ? 1.0f : 0.0f, out_spk + off);
        __builtin_nontemporal_store(v, out_mem + off);
    };

    // one 4-step group: read slots sb..sb+3, refill them, compute
    auto group = [&](int t0, int sb, bool issue) {
        float vals[12];
        #pragma unroll
        for (int k = 0; k < 4; ++k) {
            vals[k * 3 + 0] = smem[sb + k][0][tid];
            vals[k * 3 + 1] = smem[sb + k][1][tid];
            vals[k * 3 + 2] = smem[sb + k][2][tid];
        }
        // data in regs before the refill of these slots is issued
        asm volatile("s_waitcnt lgkmcnt(0)" ::: "memory");
        if (issue) issueB(t0 + 8, sb);
        #pragma unroll
        for (int k = 0; k < 4; ++k)
            step(vals[k * 3 + 0], vals[k * 3 + 1], vals[k * 3 + 2], t0 + k);
    };

    // prologue: batches B0 (slots 0-3) and B1 (slots 4-7) in flight
    issueB(0, 0);
    issueB(4, 4);

    // steady loop: groups 0..125 (each refills its slots for t0+8)
    for (int p = 0; p < 63; ++p) {
        asm volatile("s_waitcnt vmcnt(12)" ::: "memory");
        group(8 * p, 0, true);
        asm volatile("s_waitcnt vmcnt(12)" ::: "memory");
        group(8 * p + 4, 4, true);
    }
    // epilogue: groups 126, 127 (no refill)
    asm volatile("s_waitcnt vmcnt(12)" ::: "memory");
    group(504, 0, false);
    asm volatile("s_waitcnt vmcnt(0)" ::: "memory");
    group(508, 4, false);
}

extern "C" void kernel_launch(void* const* d_in, const int* in_sizes, int n_in,
                              void* d_out, int out_size, void* d_ws, size_t ws_size,
                              hipStream_t stream) {
    const float* g_exc   = (const float*)d_in[0];
    const float* g_inh   = (const float*)d_in[1];
    const float* noise   = (const float*)d_in[2];
    const float* v_th    = (const float*)d_in[3];
    const float* tau_ref = (const float*)d_in[4];

    const int N = in_sizes[3];            // 65536
    const int T = in_sizes[0] / N;        // 512

    float* out_spk = (float*)d_out;
    float* out_mem = (float*)d_out + (size_t)T * (size_t)N;

    // Constants computed in double exactly as the Python reference does.
    const double ge_decay = exp(-1.0 / 5.0);
    const double gi_decay = exp(-1.0 / 10.0);
    const double ou_alpha = exp(-1.0 / 5.0);
    const double ou_sigma = 0.02 * sqrt(1.0 - ou_alpha * ou_alpha);

    const int block = 256;
    const int grid = (N + block - 1) / block;   // 256 blocks = 1024 waves
    lif_scan<<<grid, block, 0, stream>>>(
        g_exc, g_inh, noise, v_th, tau_ref, out_spk, out_mem,
        N, T,
        (float)ge_decay, (float)gi_decay, (float)ou_alpha, (float)ou_sigma);
}